// Round 2
// baseline (2007.804 us; speedup 1.0000x reference)
//
#include <hip/hip_runtime.h>
#include <type_traits>

// ============================================================================
// CrossAttention pipeline, MI355X. Harness tensors are FP32 (ref uses float32;
// round-0 stub absmax 4.0 == max|ref| under fp32 interpretation; round-1 NaN
// == fp32 read as bf16 pairs -> Inf-Inf). Internal ws tensors are bf16.
// Geometry: B=2, C=256, H=W=256, NH=16, d=16, WS=8, hh=ww=32 -> 1024 windows/b.
// Identity: (attn@v1 + (1-attn)@v2)/2 = (attn@(v1-v2) + colsum(v2))/2
// Workspace: ~103 MB (proven within ws_size in round 1 -- no fault).
// ============================================================================

#define HW 65536     // H*W
#define WID 256

__device__ __forceinline__ float b2f(unsigned short u) {
  union { unsigned int i; float f; } c; c.i = ((unsigned int)u) << 16; return c.f;
}
__device__ __forceinline__ unsigned short f2b(float f) {
  union { float ff; unsigned int i; } c; c.ff = f;
  return (unsigned short)((c.i + 0x7FFFu + ((c.i >> 16) & 1u)) >> 16);
}

// ----------------------------------------------------------------------------
// Projection GEMM:  Out[m, p] = sum_k W[w_row0+m, k] * A[k, p],  A optionally
// A1 - A2. A: [256][65536] (AT = float or bf16-ushort). W: fp32, ld=256.
// Out: [256][65536] (OT = float or bf16-ushort).
// Tile 128 px x 128 m, 256 threads, 8x8 register micro-tile, K-chunk 8.
// ----------------------------------------------------------------------------
template <typename AT, typename OT>
__global__ __launch_bounds__(256) void gemm_proj(
    const AT* __restrict__ A1, const AT* __restrict__ A2,
    const float* __restrict__ Wt, int w_row0, OT* __restrict__ Out) {
  __shared__ __align__(16) float Xs[8][128];
  __shared__ __align__(16) float Wsh[8][128];
  const int t = threadIdx.x;
  const int hw0 = blockIdx.x * 128;   // 512 pixel tiles
  const int m0  = blockIdx.y * 128;   // 2 m tiles

  float acc[8][8];
#pragma unroll
  for (int a = 0; a < 8; ++a)
#pragma unroll
    for (int bq = 0; bq < 8; ++bq) acc[a][bq] = 0.f;

  const int px_r = (t & 15) * 8;
  const int m_r  = (t >> 4) * 8;
  const int lk   = t >> 5;            // 0..7
  const int lpx  = (t & 31) * 4;      // 0..124
  const int wm   = t & 127;           // 0..127
  const int wk4  = (t >> 7) * 4;      // 0 or 4

  for (int k0 = 0; k0 < 256; k0 += 8) {
    // stage X tile -> f32, optionally A1 - A2
    {
      const size_t off = (size_t)(k0 + lk) * HW + hw0 + lpx;
      float4 v;
      if constexpr (std::is_same_v<AT, float>) {
        v = *(const float4*)(A1 + off);
        if (A2) {
          float4 v2 = *(const float4*)(A2 + off);
          v.x -= v2.x; v.y -= v2.y; v.z -= v2.z; v.w -= v2.w;
        }
      } else {
        ushort4 u = *(const ushort4*)(A1 + off);
        v = make_float4(b2f(u.x), b2f(u.y), b2f(u.z), b2f(u.w));
      }
      *(float4*)&Xs[lk][lpx] = v;
    }
    // stage W tile transposed: Wsh[k][m]
    {
      float4 uw = *(const float4*)&Wt[(size_t)(w_row0 + m0 + wm) * 256 + k0 + wk4];
      Wsh[wk4 + 0][wm] = uw.x; Wsh[wk4 + 1][wm] = uw.y;
      Wsh[wk4 + 2][wm] = uw.z; Wsh[wk4 + 3][wm] = uw.w;
    }
    __syncthreads();
#pragma unroll
    for (int kk = 0; kk < 8; ++kk) {
      float a_[8], w_[8];
      *(float4*)&a_[0] = *(const float4*)&Xs[kk][px_r];
      *(float4*)&a_[4] = *(const float4*)&Xs[kk][px_r + 4];
      *(float4*)&w_[0] = *(const float4*)&Wsh[kk][m_r];
      *(float4*)&w_[4] = *(const float4*)&Wsh[kk][m_r + 4];
#pragma unroll
      for (int mm = 0; mm < 8; ++mm)
#pragma unroll
        for (int pp = 0; pp < 8; ++pp)
          acc[mm][pp] = fmaf(w_[mm], a_[pp], acc[mm][pp]);
    }
    __syncthreads();
  }
#pragma unroll
  for (int mm = 0; mm < 8; ++mm) {
    OT* dst = Out + (size_t)(m0 + m_r + mm) * HW + hw0 + px_r;
    if constexpr (std::is_same_v<OT, float>) {
      float4 o0 = make_float4(acc[mm][0], acc[mm][1], acc[mm][2], acc[mm][3]);
      float4 o1 = make_float4(acc[mm][4], acc[mm][5], acc[mm][6], acc[mm][7]);
      *(float4*)dst = o0; *(float4*)(dst + 4) = o1;
    } else {
      ushort4 o0, o1;
      o0.x = f2b(acc[mm][0]); o0.y = f2b(acc[mm][1]);
      o0.z = f2b(acc[mm][2]); o0.w = f2b(acc[mm][3]);
      o1.x = f2b(acc[mm][4]); o1.y = f2b(acc[mm][5]);
      o1.z = f2b(acc[mm][6]); o1.w = f2b(acc[mm][7]);
      *(ushort4*)dst = o0; *(ushort4*)(dst + 4) = o1;
    }
  }
}

// ----------------------------------------------------------------------------
// Window column-sums of x2 (fp32): S[c][wy][wx] = sum over 8x8 window.
// ----------------------------------------------------------------------------
__global__ __launch_bounds__(256) void win_colsum(
    const float* __restrict__ X2, float* __restrict__ S) {
  int idx = blockIdx.x * 256 + threadIdx.x;   // 262144 per batch item
  int wx = idx & 31, wy = (idx >> 5) & 31, c = idx >> 10;
  const float* base = X2 + (size_t)c * HW + (size_t)(wy * 8) * WID + wx * 8;
  float s = 0.f;
#pragma unroll
  for (int iy = 0; iy < 8; ++iy) {
    float4 u0 = *(const float4*)(base + iy * WID);
    float4 u1 = *(const float4*)(base + iy * WID + 4);
    s += u0.x + u0.y + u0.z + u0.w + u1.x + u1.y + u1.z + u1.w;
  }
  S[idx] = s;
}

// ----------------------------------------------------------------------------
// V2S[w][c] = sum_k Wv[c,k] * S[k][w]  (Wv = qkv_w rows 512..767, fp32)
// ----------------------------------------------------------------------------
__global__ __launch_bounds__(256) void v2s_gemm(
    const float* __restrict__ S, const float* __restrict__ Wt,
    float* __restrict__ V2S) {
  __shared__ float sv[256];
  int wpos = blockIdx.x;          // 0..1023
  int c = threadIdx.x;
  sv[c] = S[(size_t)c * 1024 + wpos];
  __syncthreads();
  const float* wr = Wt + (size_t)(512 + c) * 256;
  float acc = 0.f;
#pragma unroll 4
  for (int k = 0; k < 256; k += 8) {
    float4 a = *(const float4*)&wr[k];
    float4 b = *(const float4*)&wr[k + 4];
    acc += a.x * sv[k]     + a.y * sv[k + 1]
         + a.z * sv[k + 2] + a.w * sv[k + 3]
         + b.x * sv[k + 4] + b.y * sv[k + 5]
         + b.z * sv[k + 6] + b.w * sv[k + 7];
  }
  V2S[(size_t)wpos * 256 + c] = acc;
}

// ----------------------------------------------------------------------------
// Windowed attention, one wave per (window, head). Lane = query position i.
// Q/K/VD are bf16 workspace; output O is fp32 (d_out plane).
// o[i,dd] = 0.5 * (sum_j softmax(q.k*0.25 + bias)[j] * vd[j,dd] + v2sum[dd])
// ----------------------------------------------------------------------------
__global__ __launch_bounds__(64) void attn_win(
    const unsigned short* __restrict__ Q, const unsigned short* __restrict__ K,
    const unsigned short* __restrict__ VD, const float* __restrict__ V2S,
    const float* __restrict__ RB, float* __restrict__ O) {
  __shared__ __align__(16) float4 ks4[64][5];  // 5th float4 pads row to 80 B
  __shared__ __align__(16) float4 vs4[64][5];
  __shared__ float bs[225];
  __shared__ float v2l[16];
  const int n = blockIdx.x;        // window 0..1023
  const int h = blockIdx.y;        // head
  const int wy = n >> 5, wx = n & 31;
  const int i = threadIdx.x;       // query position
  const int iy = i >> 3, ix = i & 7;
  const size_t base = (size_t)(h * 16) * HW + (size_t)(wy * 8) * WID + wx * 8;
  const size_t pix = (size_t)iy * WID + ix;

  float q[16];
#pragma unroll
  for (int q4 = 0; q4 < 4; ++q4) {
    float4 kv, vv;
    size_t a0 = base + (size_t)(q4 * 4 + 0) * HW + pix;
    size_t a1 = base + (size_t)(q4 * 4 + 1) * HW + pix;
    size_t a2 = base + (size_t)(q4 * 4 + 2) * HW + pix;
    size_t a3 = base + (size_t)(q4 * 4 + 3) * HW + pix;
    kv.x = b2f(K[a0]); kv.y = b2f(K[a1]); kv.z = b2f(K[a2]); kv.w = b2f(K[a3]);
    vv.x = b2f(VD[a0]); vv.y = b2f(VD[a1]); vv.z = b2f(VD[a2]); vv.w = b2f(VD[a3]);
    ks4[i][q4] = kv; vs4[i][q4] = vv;
    q[q4 * 4 + 0] = b2f(Q[a0]); q[q4 * 4 + 1] = b2f(Q[a1]);
    q[q4 * 4 + 2] = b2f(Q[a2]); q[q4 * 4 + 3] = b2f(Q[a3]);
  }
  for (int r = i; r < 225; r += 64) bs[r] = RB[r * 16 + h];
  if (i < 16) v2l[i] = V2S[(size_t)n * 256 + h * 16 + i];
  __syncthreads();

  float dots[64];
  float mx = -1e30f;
#pragma unroll
  for (int j = 0; j < 64; ++j) {
    const int jy = j >> 3, jx = j & 7;
    float s = 0.f;
#pragma unroll
    for (int q4 = 0; q4 < 4; ++q4) {
      float4 kv = ks4[j][q4];
      s = fmaf(q[q4 * 4 + 0], kv.x, s); s = fmaf(q[q4 * 4 + 1], kv.y, s);
      s = fmaf(q[q4 * 4 + 2], kv.z, s); s = fmaf(q[q4 * 4 + 3], kv.w, s);
    }
    s = s * 0.25f + bs[(iy - jy + 7) * 15 + (ix - jx + 7)];
    dots[j] = s; mx = fmaxf(mx, s);
  }
  float sum = 0.f;
#pragma unroll
  for (int j = 0; j < 64; ++j) { float e = __expf(dots[j] - mx); dots[j] = e; sum += e; }
  const float inv = 1.0f / sum;
  float o[16];
#pragma unroll
  for (int dd = 0; dd < 16; ++dd) o[dd] = v2l[dd];
#pragma unroll
  for (int j = 0; j < 64; ++j) {
    float p = dots[j] * inv;
#pragma unroll
    for (int q4 = 0; q4 < 4; ++q4) {
      float4 vv = vs4[j][q4];
      o[q4 * 4 + 0] = fmaf(p, vv.x, o[q4 * 4 + 0]);
      o[q4 * 4 + 1] = fmaf(p, vv.y, o[q4 * 4 + 1]);
      o[q4 * 4 + 2] = fmaf(p, vv.z, o[q4 * 4 + 2]);
      o[q4 * 4 + 3] = fmaf(p, vv.w, o[q4 * 4 + 3]);
    }
  }
#pragma unroll
  for (int dd = 0; dd < 16; ++dd)
    O[base + (size_t)dd * HW + pix] = 0.5f * o[dd];
}

// ----------------------------------------------------------------------------
// Directional pooling: ax (8x1 vertical) + ay (1x8 horizontal), both with
// reflect-pad of 1 at the end and zero-pad 3 (count_include_pad /8), then
// zero-pad one row/col -> P [c][257][257] (bf16 ws). Input O fp32.
// ----------------------------------------------------------------------------
__global__ __launch_bounds__(256) void pool_dir(
    const float* __restrict__ O, unsigned short* __restrict__ P) {
  const int y = blockIdx.x;       // 0..256
  const int c = blockIdx.y;       // 0..255
  const int x = threadIdx.x;      // 0..255
  unsigned short* prow = P + ((size_t)c * 257 + y) * 257;
  if (y == 256) { prow[x] = 0; if (x == 0) prow[256] = 0; return; }
  const float* op = O + (size_t)c * HW;
  float ax = 0.f;
#pragma unroll
  for (int u = -3; u <= 4; ++u) {
    int t = y + u;
    if (t >= 0 && t <= 256) { int yy = (t == 256) ? 254 : t; ax += op[yy * WID + x]; }
  }
  const float* orow = op + (size_t)y * WID;
  float ay = 0.f;
#pragma unroll
  for (int u = -3; u <= 4; ++u) {
    int t = x + u;
    if (t >= 0 && t <= 256) { int xx = (t == 256) ? 254 : t; ay += orow[xx]; }
  }
  prow[x] = f2b(0.125f * (ax + ay));
  if (x == 0) prow[256] = 0;
}

// ----------------------------------------------------------------------------
// 8x8 depthwise conv (pad 3, zero) over P [c][257][257] bf16 + BN -> bf16 out.
// 64x64 output tile per block, input tile (71x71 + halo) staged in LDS.
// Conv weights / BN params are fp32 harness inputs.
// ----------------------------------------------------------------------------
__global__ __launch_bounds__(256) void dwconv_bn(
    const unsigned short* __restrict__ P, const float* __restrict__ DW,
    const float* __restrict__ G, const float* __restrict__ Bt,
    const float* __restrict__ Mn, const float* __restrict__ Vr,
    unsigned short* __restrict__ Out) {
  __shared__ float tile[71 * 72];
  __shared__ float wk[64];
  const int c = blockIdx.y;
  const int ty = (blockIdx.x >> 2) * 64, tx = (blockIdx.x & 3) * 64;
  const int t = threadIdx.x;
  if (t < 64) wk[t] = DW[c * 64 + t];
  const unsigned short* pp = P + (size_t)c * 66049;
  for (int e = t; e < 71 * 71; e += 256) {
    int iy = e / 71, ixx = e - iy * 71;
    int gy = ty + iy - 3, gx = tx + ixx - 3;
    float v = 0.f;
    if (gy >= 0 && gy < 257 && gx >= 0 && gx < 257) v = b2f(pp[(size_t)gy * 257 + gx]);
    tile[iy * 72 + ixx] = v;
  }
  __syncthreads();
  const int ox0 = (t & 15) * 4, oy0 = (t >> 4) * 4;
  float acc[4][4];
#pragma unroll
  for (int r = 0; r < 4; ++r)
#pragma unroll
    for (int cc = 0; cc < 4; ++cc) acc[r][cc] = 0.f;
  for (int ky = 0; ky < 8; ++ky) {
#pragma unroll
    for (int r = 0; r < 4; ++r) {
      const float* row = &tile[(oy0 + r + ky) * 72 + ox0];
      float rv[11];
#pragma unroll
      for (int u = 0; u < 11; ++u) rv[u] = row[u];
#pragma unroll
      for (int kx = 0; kx < 8; ++kx) {
        float wv = wk[ky * 8 + kx];
        acc[r][0] = fmaf(rv[kx + 0], wv, acc[r][0]);
        acc[r][1] = fmaf(rv[kx + 1], wv, acc[r][1]);
        acc[r][2] = fmaf(rv[kx + 2], wv, acc[r][2]);
        acc[r][3] = fmaf(rv[kx + 3], wv, acc[r][3]);
      }
    }
  }
  const float inv = G[c] * rsqrtf(Vr[c] + 1e-5f);
  const float mu = Mn[c], bb = Bt[c];
#pragma unroll
  for (int r = 0; r < 4; ++r) {
    unsigned short* dst = Out + (size_t)c * HW + (size_t)(ty + oy0 + r) * WID + (tx + ox0);
#pragma unroll
    for (int cc = 0; cc < 4; ++cc) dst[cc] = f2b((acc[r][cc] - mu) * inv + bb);
  }
}

// ----------------------------------------------------------------------------
extern "C" void kernel_launch(void* const* d_in, const int* in_sizes, int n_in,
                              void* d_out, int out_size, void* d_ws, size_t ws_size,
                              hipStream_t stream) {
  const float* x1   = (const float*)d_in[0];
  const float* x2   = (const float*)d_in[1];
  const float* qkvw = (const float*)d_in[2];
  const float* relb = (const float*)d_in[3];
  const float* dww  = (const float*)d_in[4];
  const float* g    = (const float*)d_in[5];
  const float* be   = (const float*)d_in[6];
  const float* mn   = (const float*)d_in[7];
  const float* vr   = (const float*)d_in[8];
  const float* pww  = (const float*)d_in[9];
  float* out = (float*)d_out;

  const size_t PLANE = (size_t)256 * HW;       // 16,777,216 elems / batch item
  // ws layout (bf16 intermediates, reused for both batch items sequentially):
  //   vd [16777216] | qb/P [16908544] | kb/dcbn [16777216] | S,V2S f32 [2x262144]
  // total = 103,023,104 bytes (fits: round-1 ran without fault)
  unsigned short* vd = (unsigned short*)d_ws;
  unsigned short* qb = vd + 16777216;          // q, later reused as pooled P
  unsigned short* kb = qb + 16908544;          // k, later reused as dwconv+BN out
  float* S   = (float*)(kb + 16777216);
  float* V2S = S + 262144;

  for (int b = 0; b < 2; ++b) {
    const float* x1b = x1 + (size_t)b * PLANE;
    const float* x2b = x2 + (size_t)b * PLANE;
    float* ob = out + (size_t)b * PLANE;

    gemm_proj<float, unsigned short><<<dim3(512, 2), dim3(256), 0, stream>>>(
        x1b, nullptr, qkvw, 0, qb);
    gemm_proj<float, unsigned short><<<dim3(512, 2), dim3(256), 0, stream>>>(
        x2b, nullptr, qkvw, 256, kb);
    gemm_proj<float, unsigned short><<<dim3(512, 2), dim3(256), 0, stream>>>(
        x1b, x2b, qkvw, 512, vd);
    win_colsum<<<dim3(1024), dim3(256), 0, stream>>>(x2b, S);
    v2s_gemm<<<dim3(1024), dim3(256), 0, stream>>>(S, qkvw, V2S);
    attn_win<<<dim3(1024, 16), dim3(64), 0, stream>>>(qb, kb, vd, V2S, relb, ob);
    pool_dir<<<dim3(257, 256), dim3(256), 0, stream>>>(ob, qb);   // P -> qb
    dwconv_bn<<<dim3(16, 256), dim3(256), 0, stream>>>(qb, dww, g, be, mn, vr, kb);
    gemm_proj<unsigned short, float><<<dim3(512, 2), dim3(256), 0, stream>>>(
        kb, nullptr, pww, 0, ob);
  }
}